// Round 9
// baseline (1129.907 us; speedup 1.0000x reference)
//
#include <hip/hip_runtime.h>
#include <hip/hip_bf16.h>

#define DEV __device__ __forceinline__

typedef short bf16x8 __attribute__((ext_vector_type(8)));
typedef float f32x16 __attribute__((ext_vector_type(16)));

static constexpr int FDIM  = 64;
static constexpr int HH    = 128;           // hidden/out dim
static constexpr int K1RAW = 2 * FDIM + 3;  // 131
static constexpr int K1    = 144;           // padded K for layer 1 (mult of 16)
static constexpr int KS1   = K1 / 16;       // 9 k-steps
static constexpr int KS2   = HH / 16;       // 8 k-steps
static constexpr int TM    = 128;           // edges per tile

// k-major LDS: chunk c (8 feats = 16B per row) at c*CSTR + r*16.
// CSTR = TM*16 + 16 pad -> minimal-phase LDS access everywhere.
static constexpr int CSTR  = TM * 16 + 16;         // 2064
static constexpr int MCH   = 18;                   // msg chunks (144 feats)
static constexpr int MBUF  = MCH * CSTR;           // 37152
static constexpr int HCH   = 16;                   // h chunks
static constexpr int HBUF  = HCH * CSTR;           // 33024
static constexpr int L_TOT = MBUF + HBUF + TM * 4; // 70688 -> 2 blocks/CU

static constexpr int WT1_ELEMS = HH * K1;          // 18432
static constexpr int WT2_ELEMS = HH * HH;          // 16384
static constexpr int WT_TOTAL  = WT1_ELEMS + 2 * WT2_ELEMS; // 51200

static constexpr int NBLK  = 512;                  // persistent grid (2/CU)

DEV unsigned pack2(float a, float b) {
    union { __hip_bfloat162 h; unsigned u; } cv;
    cv.h.x = __float2bfloat16(a);
    cv.h.y = __float2bfloat16(b);
    return cv.u;
}
DEV unsigned short f2bf(float f) {
    union { __hip_bfloat16 h; unsigned short u; } cv;
    cv.h = __float2bfloat16(f);
    return cv.u;
}

// ---------------- input bf16 conversion ----------------
__global__ void k_cvt(const float* __restrict__ src, unsigned short* __restrict__ dst, int n8) {
    int i = blockIdx.x * 256 + threadIdx.x;
    if (i < n8) {
        float4 a = *(const float4*)(src + (size_t)i * 8);
        float4 b = *(const float4*)(src + (size_t)i * 8 + 4);
        uint4 o;
        o.x = pack2(a.x, a.y); o.y = pack2(a.z, a.w);
        o.z = pack2(b.x, b.y); o.w = pack2(b.z, b.w);
        *(uint4*)(dst + (size_t)i * 8) = o;
    }
}

// ---------------- weight transpose + bf16 convert ----------------
__global__ void k_wprep(const float* __restrict__ W1, const float* __restrict__ W2,
                        const float* __restrict__ W3, unsigned short* __restrict__ wt) {
    int i = blockIdx.x * 256 + threadIdx.x;
    if (i < WT1_ELEMS) {
        int n = i / K1, k = i % K1;
        float v = (k < K1RAW) ? W1[k * HH + n] : 0.f;
        wt[i] = f2bf(v);
    } else if (i < WT1_ELEMS + WT2_ELEMS) {
        int j = i - WT1_ELEMS; int n = j / HH, k = j % HH;
        wt[i] = f2bf(W2[k * HH + n]);
    } else if (i < WT_TOTAL) {
        int j = i - WT1_ELEMS - WT2_ELEMS; int n = j / HH, k = j % HH;
        wt[i] = f2bf(W3[k * HH + n]);
    }
}

// ---------------- CSR build: hist -> scan -> fill ----------------
__global__ void k_hist(const int* __restrict__ edst, int* __restrict__ cnt, int E) {
    int e = blockIdx.x * 256 + threadIdx.x;
    if (e < E) atomicAdd(&cnt[edst[e]], 1);
}

__global__ void k_scan_part(const int* __restrict__ cnt, int* __restrict__ partial, int n2) {
    __shared__ int sm[256];
    int t = threadIdx.x;
    int base = blockIdx.x * 1024 + t * 4;
    int s = 0;
#pragma unroll
    for (int j = 0; j < 4; j++) { int idx = base + j; if (idx < n2) s += cnt[idx]; }
    sm[t] = s; __syncthreads();
    for (int off = 128; off > 0; off >>= 1) {
        if (t < off) sm[t] += sm[t + off];
        __syncthreads();
    }
    if (t == 0) partial[blockIdx.x] = sm[0];
}

__global__ void k_scan_top(int* __restrict__ partial, int nb) {
    __shared__ int sm[256];
    int t = threadIdx.x;
    int v = (t < nb) ? partial[t] : 0;
    sm[t] = v; __syncthreads();
    for (int off = 1; off < 256; off <<= 1) {
        int add = (t >= off) ? sm[t - off] : 0;
        __syncthreads();
        sm[t] += add;
        __syncthreads();
    }
    if (t < nb) partial[t] = sm[t] - v;   // exclusive
}

__global__ void k_scan_down(const int* __restrict__ cnt, const int* __restrict__ partial,
                            int* __restrict__ cursor, int n2) {
    __shared__ int sm[256];
    int t = threadIdx.x;
    int base = blockIdx.x * 1024 + t * 4;
    int c[4]; int s = 0;
#pragma unroll
    for (int j = 0; j < 4; j++) { int idx = base + j; c[j] = (idx < n2) ? cnt[idx] : 0; s += c[j]; }
    sm[t] = s; __syncthreads();
    for (int off = 1; off < 256; off <<= 1) {
        int add = (t >= off) ? sm[t - off] : 0;
        __syncthreads();
        sm[t] += add;
        __syncthreads();
    }
    int run = partial[blockIdx.x] + (sm[t] - s);
#pragma unroll
    for (int j = 0; j < 4; j++) {
        int idx = base + j;
        if (idx < n2) cursor[idx] = run;
        run += c[j];
    }
}

__global__ void k_fill(const int* __restrict__ edst, const int* __restrict__ esrc,
                       int* __restrict__ cursor,
                       int* __restrict__ csr_s, int* __restrict__ csr_d, int E) {
    int e = blockIdx.x * 256 + threadIdx.x;
    if (e < E) {
        int d = edst[e];
        int p = atomicAdd(&cursor[d], 1);
        csr_s[p] = esrc[e];
        csr_d[p] = d;
    }
}

// ---------------- fused MLP + segment-max (persistent, pipelined) ----------------
DEV f32x16 zerov() {
    f32x16 v;
#pragma unroll
    for (int i = 0; i < 16; i++) v[i] = 0.f;
    return v;
}

template <int KSTEPS>
DEV void load_A(const unsigned short* __restrict__ wtl, int rt, int l31, int hh, bf16x8* A) {
#pragma unroll
    for (int ks = 0; ks < KSTEPS; ks++)
        A[ks] = *(const bf16x8*)(wtl + (rt * 32 + l31) * (KSTEPS * 16) + ks * 16 + 8 * hh);
}

template <int KSTEPS>
DEV f32x16 tile_mfma(const bf16x8* A, const char* __restrict__ srcrow) {
    f32x16 acc = zerov();
#pragma unroll
    for (int ks = 0; ks < KSTEPS; ks++) {
        bf16x8 B = *(const bf16x8*)(srcrow + 2 * ks * CSTR);
        acc = __builtin_amdgcn_mfma_f32_32x32x16_bf16(A[ks], B, acc, 0, 0, 0);
    }
    return acc;
}

DEV void tile_store(const f32x16& acc, const float* __restrict__ bias, char* __restrict__ dstrow,
                    int rt, int hh) {
#pragma unroll
    for (int g = 0; g < 4; g++) {
        float4 bv = *(const float4*)(bias + rt * 32 + 8 * g + 4 * hh);
        float v0 = fmaxf(acc[4 * g + 0] + bv.x, 0.f);
        float v1 = fmaxf(acc[4 * g + 1] + bv.y, 0.f);
        float v2 = fmaxf(acc[4 * g + 2] + bv.z, 0.f);
        float v3 = fmaxf(acc[4 * g + 3] + bv.w, 0.f);
        uint2 w; w.x = pack2(v0, v1); w.y = pack2(v2, v3);
        *(uint2*)(dstrow + g * CSTR) = w;
    }
}

template <bool SORTED, bool BF16SRC>
__global__ __launch_bounds__(512, 4) void k_main(
    const float* __restrict__ x1f, const float* __restrict__ x1p,
    const float* __restrict__ x2f, const float* __restrict__ x2p,
    const char* __restrict__ xb1, const char* __restrict__ xb2,
    const float* __restrict__ b1, const float* __restrict__ b2, const float* __restrict__ b3,
    const unsigned short* __restrict__ wt,
    const int* __restrict__ csr_s, const int* __restrict__ csr_d,
    const int* __restrict__ edge_src, const int* __restrict__ edge_dst,
    float* __restrict__ out, int E) {
    __shared__ __align__(16) char smem[L_TOT];
    char* msg = smem;
    char* hbf = smem + MBUF;
    int*  dl  = (int*)(smem + MBUF + HBUF);

    const int tid  = threadIdx.x;
    const int lane = tid & 63;
    const int wv   = tid >> 6;    // 0..7
    const int l31  = lane & 31;
    const int hh   = lane >> 5;
    const int r    = tid >> 2;    // staging row 0..127
    const int sub  = tid & 3;
    const int rt   = wv & 3;         // feature tile
    const int ct0  = (wv >> 2) * 2;  // edge tile pair base
    const int ntiles = (E + TM - 1) / TM;
    const int nb     = (int)gridDim.x;

    // index load for tile; d=-1 marks invalid row
    auto load_idx = [&](int tile, int& d, int& s) {
        const int slot = tile * TM + r;
        const bool ok = (tile < ntiles) && (slot < E);
        d = ok ? (SORTED ? csr_d[slot] : edge_dst[slot]) : -1;
        s = ok ? (SORTED ? csr_s[slot] : edge_src[slot]) : 0;
    };
    // feature/pos loads for this thread's chunks of its row
    auto load_feats = [&](int d, int s, uint4* v, float* pp) {
#pragma unroll
        for (int i = 0; i < 4; i++) { v[i].x = v[i].y = v[i].z = v[i].w = 0u; }
        pp[0] = pp[1] = pp[2] = pp[3] = pp[4] = pp[5] = 0.f;
        if (d >= 0) {
            if (BF16SRC) {
                const char* base = (sub < 2) ? (xb2 + (size_t)d * (2 * FDIM))
                                             : (xb1 + (size_t)s * (2 * FDIM));
#pragma unroll
                for (int i = 0; i < 4; i++)
                    v[i] = *(const uint4*)(base + ((sub & 1) * 4 + i) * 16);
            } else {
                const float* base = (sub < 2) ? (x2f + (size_t)d * FDIM)
                                              : (x1f + (size_t)s * FDIM);
#pragma unroll
                for (int i = 0; i < 4; i++) {
                    const int cc = (sub & 1) * 4 + i;
                    float4 a = *(const float4*)(base + cc * 8);
                    float4 b = *(const float4*)(base + cc * 8 + 4);
                    v[i].x = pack2(a.x, a.y); v[i].y = pack2(a.z, a.w);
                    v[i].z = pack2(b.x, b.y); v[i].w = pack2(b.z, b.w);
                }
            }
            if (sub == 3) {
                pp[0] = x1p[s * 3 + 0]; pp[1] = x1p[s * 3 + 1]; pp[2] = x1p[s * 3 + 2];
                pp[3] = x2p[d * 3 + 0]; pp[4] = x2p[d * 3 + 1]; pp[5] = x2p[d * 3 + 2];
            }
        }
    };

    // ---- pipeline prologue ----
    int tile = (int)blockIdx.x;
    int d0, s0, d1, s1;
    uint4 v0[4]; float p0[6];
    load_idx(tile, d0, s0);
    load_feats(d0, s0, v0, p0);
    load_idx(tile + nb, d1, s1);

    for (int t = tile; t < ntiles; t += nb) {
        // ---- write staged tile t into LDS ----
        __syncthreads();   // prev iter's readers (L3/segmax) done
        {
            char* colbase = msg + r * 16 + (sub * 4) * CSTR;
#pragma unroll
            for (int i = 0; i < 4; i++)
                *(uint4*)(colbase + i * CSTR) = v0[i];
            if (sub == 3) {
                uint4 v; v.x = pack2(p0[0] - p0[3], p0[1] - p0[4]);
                v.y = pack2(p0[2] - p0[5], 0.f); v.z = 0u; v.w = 0u;
                *(uint4*)(msg + r * 16 + 16 * CSTR) = v;
                uint4 z; z.x = z.y = z.z = z.w = 0u;
                *(uint4*)(msg + r * 16 + 17 * CSTR) = z;
            }
            if (sub == 0) dl[r] = d0;
        }
        __syncthreads();

        // ---- issue next tile's gathers (overlap with compute below) ----
        uint4 v1[4]; float p1[6];
        load_feats(d1, s1, v1, p1);
        int d2, s2;
        load_idx(t + 2 * nb, d2, s2);

        // ---- layer 1: msg (K=144) -> hbf ----
        {
            bf16x8 A[KS1];
            load_A<KS1>(wt, rt, l31, hh, A);
#pragma unroll
            for (int j = 0; j < 2; j++) {
                const int rr = (ct0 + j) * 32 + l31;
                f32x16 acc = tile_mfma<KS1>(A, msg + rr * 16 + hh * CSTR);
                tile_store(acc, b1, hbf + rr * 16 + 8 * hh + (4 * rt) * CSTR, rt, hh);
            }
        }
        __syncthreads();

        // ---- layer 2: hbf -> msg chunks 0..15 (dead until next stage) ----
        {
            bf16x8 A[KS2];
            load_A<KS2>(wt + WT1_ELEMS, rt, l31, hh, A);
#pragma unroll
            for (int j = 0; j < 2; j++) {
                const int rr = (ct0 + j) * 32 + l31;
                f32x16 acc = tile_mfma<KS2>(A, hbf + rr * 16 + hh * CSTR);
                tile_store(acc, b2, msg + rr * 16 + 8 * hh + (4 * rt) * CSTR, rt, hh);
            }
        }
        __syncthreads();

        // ---- layer 3: msg -> hbf ----
        {
            bf16x8 A[KS2];
            load_A<KS2>(wt + WT1_ELEMS + WT2_ELEMS, rt, l31, hh, A);
#pragma unroll
            for (int j = 0; j < 2; j++) {
                const int rr = (ct0 + j) * 32 + l31;
                f32x16 acc = tile_mfma<KS2>(A, msg + rr * 16 + hh * CSTR);
                tile_store(acc, b3, hbf + rr * 16 + 8 * hh + (4 * rt) * CSTR, rt, hh);
            }
        }
        __syncthreads();

        // ---- segment-max: 2 feats/thread, 8 strips of 16 rows ----
        {
            const int p     = tid & 63;
            const int strip = tid >> 6;
            const int r0 = strip * 16;
            const char* fbase = hbf + (p >> 2) * CSTR + (p & 3) * 4;
            int curd = dl[r0];
            int rs = r0;
            float m0 = 0.f, m1 = 0.f;
#pragma unroll
            for (int rr = r0; rr < r0 + 16; rr++) {
                int d = dl[rr];
                if (d != curd) {
                    if (curd >= 0) {
                        bool extL = (rs == r0) && (r0 == 0 || dl[r0 - 1] == curd);
                        if (extL) {
                            if (m0 > 0.f) atomicMax((int*)out + (size_t)curd * HH + 2 * p,     __float_as_int(m0));
                            if (m1 > 0.f) atomicMax((int*)out + (size_t)curd * HH + 2 * p + 1, __float_as_int(m1));
                        } else {
                            out[(size_t)curd * HH + 2 * p]     = m0;
                            out[(size_t)curd * HH + 2 * p + 1] = m1;
                        }
                    }
                    curd = d; rs = rr; m0 = 0.f; m1 = 0.f;
                }
                unsigned w = *(const unsigned*)(fbase + rr * 16);
                m0 = fmaxf(m0, __uint_as_float(w << 16));
                m1 = fmaxf(m1, __uint_as_float(w & 0xffff0000u));
            }
            if (curd >= 0) {
                bool extL = (rs == r0) && (r0 == 0 || dl[r0 - 1] == curd);
                bool extR = (r0 + 16 == TM) || (dl[r0 + 16] == curd);
                if (extL || extR) {
                    if (m0 > 0.f) atomicMax((int*)out + (size_t)curd * HH + 2 * p,     __float_as_int(m0));
                    if (m1 > 0.f) atomicMax((int*)out + (size_t)curd * HH + 2 * p + 1, __float_as_int(m1));
                } else {
                    out[(size_t)curd * HH + 2 * p]     = m0;
                    out[(size_t)curd * HH + 2 * p + 1] = m1;
                }
            }
        }

        // ---- rotate pipeline registers ----
        d0 = d1; s0 = s1;
#pragma unroll
        for (int i = 0; i < 4; i++) v0[i] = v1[i];
#pragma unroll
        for (int i = 0; i < 6; i++) p0[i] = p1[i];
        d1 = d2; s1 = s2;
    }
}

extern "C" void kernel_launch(void* const* d_in, const int* in_sizes, int n_in,
                              void* d_out, int out_size, void* d_ws, size_t ws_size,
                              hipStream_t stream) {
    const float* x1f = (const float*)d_in[0];
    const float* x1p = (const float*)d_in[1];
    const float* x2f = (const float*)d_in[2];
    const float* x2p = (const float*)d_in[3];
    const float* W1  = (const float*)d_in[4];
    const float* b1  = (const float*)d_in[5];
    const float* W2  = (const float*)d_in[6];
    const float* b2  = (const float*)d_in[7];
    const float* W3  = (const float*)d_in[8];
    const float* b3  = (const float*)d_in[9];
    const int* esrc  = (const int*)d_in[10];
    const int* edst  = (const int*)d_in[11];
    const int E  = in_sizes[10];
    const int N1 = in_sizes[1] / 3;
    const int N2 = in_sizes[3] / 3;
    float* out = (float*)d_out;

    // workspace layout
    size_t off = 0;
    auto take = [&](size_t bytes) { size_t o = off; off = (off + bytes + 255) & ~(size_t)255; return o; };
    size_t o_cnt = take(4 * (size_t)N2);
    size_t o_cur = take(4 * (size_t)N2);
    size_t o_par = take(4 * 256);
    size_t o_cs  = take(4 * (size_t)E);
    size_t o_cd  = take(4 * (size_t)E);
    size_t o_wt  = take(2 * (size_t)WT_TOTAL);
    size_t need_csr = off;
    size_t o_x1  = take(2 * (size_t)N1 * FDIM);
    size_t o_x2  = take(2 * (size_t)N2 * FDIM);
    size_t need_bf = off;

    const int NB = (N2 + 1023) / 1024;
    bool use_csr = (need_csr <= ws_size) && (NB <= 256);
    bool use_bf  = (need_bf <= ws_size);

    char* ws = (char*)d_ws;
    unsigned short* wt = use_csr ? (unsigned short*)(ws + o_wt) : (unsigned short*)ws;
    int* cnt    = (int*)(ws + o_cnt);
    int* cursor = (int*)(ws + o_cur);
    int* part   = (int*)(ws + o_par);
    int* csr_s  = (int*)(ws + o_cs);
    int* csr_d  = (int*)(ws + o_cd);
    char* xb1   = ws + o_x1;
    char* xb2   = ws + o_x2;

    // output init: zero aggregate region, copy x2_pos into tail
    (void)hipMemsetAsync(out, 0, (size_t)N2 * HH * 4, stream);
    (void)hipMemcpyAsync(out + (size_t)N2 * HH, x2p, (size_t)N2 * 3 * 4,
                         hipMemcpyDeviceToDevice, stream);

    k_wprep<<<(WT_TOTAL + 255) / 256, 256, 0, stream>>>(W1, W2, W3, wt);

    if (use_bf) {
        int n8_1 = N1 * FDIM / 8, n8_2 = N2 * FDIM / 8;
        k_cvt<<<(n8_1 + 255) / 256, 256, 0, stream>>>(x1f, (unsigned short*)xb1, n8_1);
        k_cvt<<<(n8_2 + 255) / 256, 256, 0, stream>>>(x2f, (unsigned short*)xb2, n8_2);
    }

    const int ntiles = (E + TM - 1) / TM;
    const int grid = (ntiles < NBLK) ? ntiles : NBLK;
    if (use_csr) {
        (void)hipMemsetAsync(cnt, 0, 4 * (size_t)N2, stream);
        k_hist<<<(E + 255) / 256, 256, 0, stream>>>(edst, cnt, E);
        k_scan_part<<<NB, 256, 0, stream>>>(cnt, part, N2);
        k_scan_top<<<1, 256, 0, stream>>>(part, NB);
        k_scan_down<<<NB, 256, 0, stream>>>(cnt, part, cursor, N2);
        k_fill<<<(E + 255) / 256, 256, 0, stream>>>(edst, esrc, cursor, csr_s, csr_d, E);
        if (use_bf)
            k_main<true, true><<<grid, 512, 0, stream>>>(
                x1f, x1p, x2f, x2p, xb1, xb2, b1, b2, b3, wt, csr_s, csr_d, esrc, edst, out, E);
        else
            k_main<true, false><<<grid, 512, 0, stream>>>(
                x1f, x1p, x2f, x2p, xb1, xb2, b1, b2, b3, wt, csr_s, csr_d, esrc, edst, out, E);
    } else {
        if (use_bf)
            k_main<false, true><<<grid, 512, 0, stream>>>(
                x1f, x1p, x2f, x2p, xb1, xb2, b1, b2, b3, wt, edst, edst, esrc, edst, out, E);
        else
            k_main<false, false><<<grid, 512, 0, stream>>>(
                x1f, x1p, x2f, x2p, xb1, xb2, b1, b2, b3, wt, edst, edst, esrc, edst, out, E);
    }
}

// Round 10
// 616.038 us; speedup vs baseline: 1.8342x; 1.8342x over previous
//
#include <hip/hip_runtime.h>
#include <hip/hip_bf16.h>

#define DEV __device__ __forceinline__

typedef short bf16x8 __attribute__((ext_vector_type(8)));
typedef float f32x16 __attribute__((ext_vector_type(16)));

static constexpr int FDIM  = 64;
static constexpr int HH    = 128;
static constexpr int KPAD  = 144;          // padded K for ALL layers (bias row folded in)
static constexpr int KS    = KPAD / 16;    // 9
static constexpr int TM    = 256;          // edges per block (8 waves x 32)

// h3 LDS: k-major, chunk c at c*CSTR, row r at 16*r + 8*(r>>3) skew (+8hh half)
static constexpr int CSTR  = TM * 16 + 256 + 16;   // 4368
static constexpr int HBUF  = 16 * CSTR;            // 69888
static constexpr int L_TOT = HBUF + TM * 4;        // 70912 -> 2 blocks/CU

static constexpr int WTL      = KPAD * HH;         // 18432 per layer
static constexpr int WT_TOTAL = 3 * WTL;           // 55296

DEV unsigned pack2(float a, float b) {
    union { __hip_bfloat162 h; unsigned u; } cv;
    cv.h.x = __float2bfloat16(a);
    cv.h.y = __float2bfloat16(b);
    return cv.u;
}
DEV unsigned short f2bf(float f) {
    union { __hip_bfloat16 h; unsigned short u; } cv;
    cv.h = __float2bfloat16(f);
    return cv.u;
}
DEV int rowoff(int r) { return r * 16 + (r >> 3) * 8; }

// ---------------- input bf16 conversion ----------------
__global__ void k_cvt(const float* __restrict__ src, unsigned short* __restrict__ dst, int n8) {
    int i = blockIdx.x * 256 + threadIdx.x;
    if (i < n8) {
        float4 a = *(const float4*)(src + (size_t)i * 8);
        float4 b = *(const float4*)(src + (size_t)i * 8 + 4);
        uint4 o;
        o.x = pack2(a.x, a.y); o.y = pack2(a.z, a.w);
        o.z = pack2(b.x, b.y); o.w = pack2(b.z, b.w);
        *(uint4*)(dst + (size_t)i * 8) = o;
    }
}

// ---------------- weights: transpose + bf16 + bias folded as K-row ----------------
__global__ void k_wprep(const float* __restrict__ W1, const float* __restrict__ b1,
                        const float* __restrict__ W2, const float* __restrict__ b2,
                        const float* __restrict__ W3, const float* __restrict__ b3,
                        unsigned short* __restrict__ wt) {
    int i = blockIdx.x * 256 + threadIdx.x;
    if (i >= WT_TOTAL) return;
    int layer = i / WTL, j = i % WTL;
    int n = j / KPAD, k = j % KPAD;
    float v = 0.f;
    if (layer == 0) {
        if (k < 131) v = W1[k * HH + n];
        else if (k == 131) v = b1[n];          // msg feature 131 == 1.0
    } else {
        const float* W = (layer == 1) ? W2 : W3;
        const float* b = (layer == 1) ? b2 : b3;
        if (k < 128) v = W[k * HH + n];
        else if (k == 128) v = b[n];           // h feature 128 == 1.0
    }
    wt[i] = f2bf(v);
}

// ---------------- CSR build: hist -> scan -> fill ----------------
__global__ void k_hist(const int* __restrict__ edst, int* __restrict__ cnt, int E) {
    int e = blockIdx.x * 256 + threadIdx.x;
    if (e < E) atomicAdd(&cnt[edst[e]], 1);
}

__global__ void k_scan_part(const int* __restrict__ cnt, int* __restrict__ partial, int n2) {
    __shared__ int sm[256];
    int t = threadIdx.x;
    int base = blockIdx.x * 1024 + t * 4;
    int s = 0;
#pragma unroll
    for (int j = 0; j < 4; j++) { int idx = base + j; if (idx < n2) s += cnt[idx]; }
    sm[t] = s; __syncthreads();
    for (int off = 128; off > 0; off >>= 1) {
        if (t < off) sm[t] += sm[t + off];
        __syncthreads();
    }
    if (t == 0) partial[blockIdx.x] = sm[0];
}

__global__ void k_scan_top(int* __restrict__ partial, int nb) {
    __shared__ int sm[256];
    int t = threadIdx.x;
    int v = (t < nb) ? partial[t] : 0;
    sm[t] = v; __syncthreads();
    for (int off = 1; off < 256; off <<= 1) {
        int add = (t >= off) ? sm[t - off] : 0;
        __syncthreads();
        sm[t] += add;
        __syncthreads();
    }
    if (t < nb) partial[t] = sm[t] - v;   // exclusive
}

__global__ void k_scan_down(const int* __restrict__ cnt, const int* __restrict__ partial,
                            int* __restrict__ cursor, int n2) {
    __shared__ int sm[256];
    int t = threadIdx.x;
    int base = blockIdx.x * 1024 + t * 4;
    int c[4]; int s = 0;
#pragma unroll
    for (int j = 0; j < 4; j++) { int idx = base + j; c[j] = (idx < n2) ? cnt[idx] : 0; s += c[j]; }
    sm[t] = s; __syncthreads();
    for (int off = 1; off < 256; off <<= 1) {
        int add = (t >= off) ? sm[t - off] : 0;
        __syncthreads();
        sm[t] += add;
        __syncthreads();
    }
    int run = partial[blockIdx.x] + (sm[t] - s);
#pragma unroll
    for (int j = 0; j < 4; j++) {
        int idx = base + j;
        if (idx < n2) cursor[idx] = run;
        run += c[j];
    }
}

__global__ void k_fill(const int* __restrict__ edst, const int* __restrict__ esrc,
                       int* __restrict__ cursor,
                       int* __restrict__ csr_s, int* __restrict__ csr_d, int E) {
    int e = blockIdx.x * 256 + threadIdx.x;
    if (e < E) {
        int d = edst[e];
        int p = atomicAdd(&cursor[d], 1);
        csr_s[p] = esrc[e];
        csr_d[p] = d;
    }
}

// ---------------- register-resident MLP ----------------
DEV f32x16 zerov() {
    f32x16 v;
#pragma unroll
    for (int i = 0; i < 16; i++) v[i] = 0.f;
    return v;
}
DEV float relu(float x) { return fmaxf(x, 0.f); }

// hidden layer fully in registers. pkin: 32 dwords (feats 8u+4hh+{0..3} packed),
// pkout: same layout for the next layer. 16 batched shfl_xor(32) do the
// half-feature exchange; bias comes from weight row 128 (activation "1.0").
DEV void layer_reg(const unsigned short* __restrict__ wtl, const unsigned pkin[32],
                   unsigned pkout[32], int l31, int hh, unsigned biasw) {
    unsigned xv[16];
#pragma unroll
    for (int ks = 0; ks < 8; ks++) {
        unsigned t0 = hh ? pkin[4 * ks + 0] : pkin[4 * ks + 2];
        unsigned t1 = hh ? pkin[4 * ks + 1] : pkin[4 * ks + 3];
        xv[2 * ks + 0] = (unsigned)__shfl_xor((int)t0, 32, 64);
        xv[2 * ks + 1] = (unsigned)__shfl_xor((int)t1, 32, 64);
    }
#pragma unroll
    for (int rt = 0; rt < 4; rt++) {
        f32x16 acc = zerov();
#pragma unroll
        for (int ks = 0; ks < 8; ks++) {
            union { unsigned u[4]; bf16x8 v; } B;
            B.u[0] = hh ? xv[2 * ks + 0]   : pkin[4 * ks + 0];
            B.u[1] = hh ? xv[2 * ks + 1]   : pkin[4 * ks + 1];
            B.u[2] = hh ? pkin[4 * ks + 2] : xv[2 * ks + 0];
            B.u[3] = hh ? pkin[4 * ks + 3] : xv[2 * ks + 1];
            bf16x8 A = *(const bf16x8*)(wtl + (rt * 32 + l31) * KPAD + ks * 16 + 8 * hh);
            acc = __builtin_amdgcn_mfma_f32_32x32x16_bf16(A, B.v, acc, 0, 0, 0);
        }
        {   // ks = 8: bias row (feature 128 = 1.0, rest 0)
            union { unsigned u[4]; bf16x8 v; } B;
            B.u[0] = biasw; B.u[1] = 0u; B.u[2] = 0u; B.u[3] = 0u;
            bf16x8 A = *(const bf16x8*)(wtl + (rt * 32 + l31) * KPAD + 8 * 16 + 8 * hh);
            acc = __builtin_amdgcn_mfma_f32_32x32x16_bf16(A, B.v, acc, 0, 0, 0);
        }
#pragma unroll
        for (int g = 0; g < 4; g++) {
            pkout[8 * rt + 2 * g + 0] = pack2(relu(acc[4 * g + 0]), relu(acc[4 * g + 1]));
            pkout[8 * rt + 2 * g + 1] = pack2(relu(acc[4 * g + 2]), relu(acc[4 * g + 3]));
        }
    }
}

template <bool SORTED, bool BF16SRC>
__global__ __launch_bounds__(512, 4) void k_main(
    const float* __restrict__ x1f, const float* __restrict__ x1p,
    const float* __restrict__ x2f, const float* __restrict__ x2p,
    const char* __restrict__ xb1, const char* __restrict__ xb2,
    const unsigned short* __restrict__ wt,
    const int* __restrict__ csr_s, const int* __restrict__ csr_d,
    const int* __restrict__ edge_src, const int* __restrict__ edge_dst,
    float* __restrict__ out, int E) {
    __shared__ __align__(16) char smem[L_TOT];
    char* hbf = smem;
    int*  dl  = (int*)(smem + HBUF);

    const int tid  = threadIdx.x;
    const int lane = tid & 63;
    const int wv   = tid >> 6;    // 0..7
    const int l31  = lane & 31;
    const int hh   = lane >> 5;
    const int eb   = blockIdx.x * TM;
    const int r    = wv * 32 + l31;      // this lane's edge row in block
    const int slot = eb + r;
    const bool ok  = slot < E;

    int d = 0, s = 0;
    if (ok) {
        d = SORTED ? csr_d[slot] : edge_dst[slot];
        s = SORTED ? csr_s[slot] : edge_src[slot];
    }
    if (hh == 0) dl[r] = ok ? d : -1;

    // ---- gather layer-1 B fragments straight into registers ----
    bf16x8 Bv[KS];
    if (BF16SRC) {
        const char* bx2 = xb2 + (size_t)d * (2 * FDIM);
        const char* bx1 = xb1 + (size_t)s * (2 * FDIM);
#pragma unroll
        for (int ks = 0; ks < 4; ks++)
            Bv[ks] = *(const bf16x8*)(bx2 + (2 * ks + hh) * 16);
#pragma unroll
        for (int ks = 4; ks < 8; ks++)
            Bv[ks] = *(const bf16x8*)(bx1 + (2 * (ks - 4) + hh) * 16);
    } else {
        const float* fx2 = x2f + (size_t)d * FDIM;
        const float* fx1 = x1f + (size_t)s * FDIM;
#pragma unroll
        for (int ks = 0; ks < 8; ks++) {
            const float* b = (ks < 4) ? (fx2 + (2 * ks + hh) * 8)
                                      : (fx1 + (2 * (ks - 4) + hh) * 8);
            float4 a0 = *(const float4*)(b);
            float4 a1 = *(const float4*)(b + 4);
            union { unsigned u[4]; bf16x8 v; } B;
            B.u[0] = pack2(a0.x, a0.y); B.u[1] = pack2(a0.z, a0.w);
            B.u[2] = pack2(a1.x, a1.y); B.u[3] = pack2(a1.z, a1.w);
            Bv[ks] = B.v;
        }
    }
    {
        float dx = 0.f, dy = 0.f, dz = 0.f;
        if (ok) {
            dx = x1p[s * 3 + 0] - x2p[d * 3 + 0];
            dy = x1p[s * 3 + 1] - x2p[d * 3 + 1];
            dz = x1p[s * 3 + 2] - x2p[d * 3 + 2];
        }
        union { unsigned u[4]; bf16x8 v; } P;
        P.u[0] = hh ? 0u : pack2(dx, dy);
        P.u[1] = hh ? 0u : pack2(dz, 1.0f);   // feature 131 = 1.0 (bias multiplier)
        P.u[2] = 0u; P.u[3] = 0u;
        Bv[8] = P.v;
    }

    // ---- layer 1 (K=144, bias folded) -> pkA ----
    unsigned pkA[32], pkB[32];
#pragma unroll
    for (int rt = 0; rt < 4; rt++) {
        f32x16 acc = zerov();
#pragma unroll
        for (int ks = 0; ks < KS; ks++) {
            bf16x8 A = *(const bf16x8*)(wt + (rt * 32 + l31) * KPAD + ks * 16 + 8 * hh);
            acc = __builtin_amdgcn_mfma_f32_32x32x16_bf16(A, Bv[ks], acc, 0, 0, 0);
        }
#pragma unroll
        for (int g = 0; g < 4; g++) {
            pkA[8 * rt + 2 * g + 0] = pack2(relu(acc[4 * g + 0]), relu(acc[4 * g + 1]));
            pkA[8 * rt + 2 * g + 1] = pack2(relu(acc[4 * g + 2]), relu(acc[4 * g + 3]));
        }
    }

    const unsigned biasw = hh ? 0u : 0x00003F80u;  // bf16 1.0 at feature 128
    // ---- layer 2 / layer 3 fully in registers ----
    layer_reg(wt + WTL,     pkA, pkB, l31, hh, biasw);
    layer_reg(wt + 2 * WTL, pkB, pkA, l31, hh, biasw);

    // ---- h3 -> LDS (skewed k-major) ----
    {
        char* dst = hbf + rowoff(r) + 8 * hh;
#pragma unroll
        for (int u = 0; u < 16; u++) {
            uint2 w; w.x = pkA[2 * u + 0]; w.y = pkA[2 * u + 1];
            *(uint2*)(dst + u * CSTR) = w;
        }
    }
    __syncthreads();

    // ---- segment-max: 2 feats/thread, 8 strips of 32 rows ----
    {
        const int p     = tid & 63;   // feature pair: feats 2p, 2p+1
        const int strip = tid >> 6;   // 0..7
        const int r0 = strip * 32;
        const char* fbase = hbf + (p >> 2) * CSTR + (p & 3) * 4;
        int curd = dl[r0];
        int rs = r0;
        float m0 = 0.f, m1 = 0.f;
#pragma unroll 4
        for (int rr = r0; rr < r0 + 32; rr++) {
            int dd = dl[rr];
            if (dd != curd) {
                if (curd >= 0) {
                    bool extL = (rs == r0) && (r0 == 0 || dl[r0 - 1] == curd);
                    if (extL) {
                        if (m0 > 0.f) atomicMax((int*)out + (size_t)curd * HH + 2 * p,     __float_as_int(m0));
                        if (m1 > 0.f) atomicMax((int*)out + (size_t)curd * HH + 2 * p + 1, __float_as_int(m1));
                    } else {
                        out[(size_t)curd * HH + 2 * p]     = m0;
                        out[(size_t)curd * HH + 2 * p + 1] = m1;
                    }
                }
                curd = dd; rs = rr; m0 = 0.f; m1 = 0.f;
            }
            unsigned w = *(const unsigned*)(fbase + rowoff(rr));
            m0 = fmaxf(m0, __uint_as_float(w << 16));
            m1 = fmaxf(m1, __uint_as_float(w & 0xffff0000u));
        }
        if (curd >= 0) {
            bool extL = (rs == r0) && (r0 == 0 || dl[r0 - 1] == curd);
            bool extR = (r0 + 32 == TM) || (dl[r0 + 32] == curd);
            if (extL || extR) {
                if (m0 > 0.f) atomicMax((int*)out + (size_t)curd * HH + 2 * p,     __float_as_int(m0));
                if (m1 > 0.f) atomicMax((int*)out + (size_t)curd * HH + 2 * p + 1, __float_as_int(m1));
            } else {
                out[(size_t)curd * HH + 2 * p]     = m0;
                out[(size_t)curd * HH + 2 * p + 1] = m1;
            }
        }
    }
}

extern "C" void kernel_launch(void* const* d_in, const int* in_sizes, int n_in,
                              void* d_out, int out_size, void* d_ws, size_t ws_size,
                              hipStream_t stream) {
    const float* x1f = (const float*)d_in[0];
    const float* x1p = (const float*)d_in[1];
    const float* x2f = (const float*)d_in[2];
    const float* x2p = (const float*)d_in[3];
    const float* W1  = (const float*)d_in[4];
    const float* b1  = (const float*)d_in[5];
    const float* W2  = (const float*)d_in[6];
    const float* b2  = (const float*)d_in[7];
    const float* W3  = (const float*)d_in[8];
    const float* b3  = (const float*)d_in[9];
    const int* esrc  = (const int*)d_in[10];
    const int* edst  = (const int*)d_in[11];
    const int E  = in_sizes[10];
    const int N1 = in_sizes[1] / 3;
    const int N2 = in_sizes[3] / 3;
    float* out = (float*)d_out;

    // workspace layout
    size_t off = 0;
    auto take = [&](size_t bytes) { size_t o = off; off = (off + bytes + 255) & ~(size_t)255; return o; };
    size_t o_cnt = take(4 * (size_t)N2);
    size_t o_cur = take(4 * (size_t)N2);
    size_t o_par = take(4 * 256);
    size_t o_cs  = take(4 * (size_t)E);
    size_t o_cd  = take(4 * (size_t)E);
    size_t o_wt  = take(2 * (size_t)WT_TOTAL);
    size_t need_csr = off;
    size_t o_x1  = take(2 * (size_t)N1 * FDIM);
    size_t o_x2  = take(2 * (size_t)N2 * FDIM);
    size_t need_bf = off;

    const int NB = (N2 + 1023) / 1024;
    bool use_csr = (need_csr <= ws_size) && (NB <= 256);
    bool use_bf  = (need_bf <= ws_size);

    char* ws = (char*)d_ws;
    unsigned short* wt = use_csr ? (unsigned short*)(ws + o_wt) : (unsigned short*)ws;
    int* cnt    = (int*)(ws + o_cnt);
    int* cursor = (int*)(ws + o_cur);
    int* part   = (int*)(ws + o_par);
    int* csr_s  = (int*)(ws + o_cs);
    int* csr_d  = (int*)(ws + o_cd);
    char* xb1   = ws + o_x1;
    char* xb2   = ws + o_x2;

    // output init: zero aggregate region, copy x2_pos into tail
    (void)hipMemsetAsync(out, 0, (size_t)N2 * HH * 4, stream);
    (void)hipMemcpyAsync(out + (size_t)N2 * HH, x2p, (size_t)N2 * 3 * 4,
                         hipMemcpyDeviceToDevice, stream);

    k_wprep<<<(WT_TOTAL + 255) / 256, 256, 0, stream>>>(W1, b1, W2, b2, W3, b3, wt);

    if (use_bf) {
        int n8_1 = N1 * FDIM / 8, n8_2 = N2 * FDIM / 8;
        k_cvt<<<(n8_1 + 255) / 256, 256, 0, stream>>>(x1f, (unsigned short*)xb1, n8_1);
        k_cvt<<<(n8_2 + 255) / 256, 256, 0, stream>>>(x2f, (unsigned short*)xb2, n8_2);
    }

    const int grid = (E + TM - 1) / TM;
    if (use_csr) {
        (void)hipMemsetAsync(cnt, 0, 4 * (size_t)N2, stream);
        k_hist<<<(E + 255) / 256, 256, 0, stream>>>(edst, cnt, E);
        k_scan_part<<<NB, 256, 0, stream>>>(cnt, part, N2);
        k_scan_top<<<1, 256, 0, stream>>>(part, NB);
        k_scan_down<<<NB, 256, 0, stream>>>(cnt, part, cursor, N2);
        k_fill<<<(E + 255) / 256, 256, 0, stream>>>(edst, esrc, cursor, csr_s, csr_d, E);
        if (use_bf)
            k_main<true, true><<<grid, 512, 0, stream>>>(
                x1f, x1p, x2f, x2p, xb1, xb2, wt, csr_s, csr_d, esrc, edst, out, E);
        else
            k_main<true, false><<<grid, 512, 0, stream>>>(
                x1f, x1p, x2f, x2p, xb1, xb2, wt, csr_s, csr_d, esrc, edst, out, E);
    } else {
        if (use_bf)
            k_main<false, true><<<grid, 512, 0, stream>>>(
                x1f, x1p, x2f, x2p, xb1, xb2, wt, edst, edst, esrc, edst, out, E);
        else
            k_main<false, false><<<grid, 512, 0, stream>>>(
                x1f, x1p, x2f, x2p, xb1, xb2, wt, edst, edst, esrc, edst, out, E);
    }
}